// Round 2
// baseline (58.872 us; speedup 1.0000x reference)
//
#include <hip/hip_runtime.h>
#include <string.h>

#define B_N 8192
#define K_CL 64
#define INF_F 3.0e38f

// ws layout (floats): [0,8192) sortedX | [8192,16384) sortedY |
// [16384,16449) start offsets (int, 65)

__global__ __launch_bounds__(1024) void sort_by_label_kernel(
    const int* __restrict__ labels, const float* __restrict__ coords,
    float* __restrict__ sx, float* __restrict__ sy, int* __restrict__ start) {
    __shared__ int cnt[K_CL];
    __shared__ int base[K_CL];
    int tid = threadIdx.x;
    if (tid < K_CL) cnt[tid] = 0;
    __syncthreads();

    // 8 labels per thread via two int4 loads (coalesced 16B/lane)
    int4 la = reinterpret_cast<const int4*>(labels)[2 * tid];
    int4 lb = reinterpret_cast<const int4*>(labels)[2 * tid + 1];
    int l[8] = {la.x, la.y, la.z, la.w, lb.x, lb.y, lb.z, lb.w};
#pragma unroll
    for (int k = 0; k < 8; ++k) atomicAdd(&cnt[l[k]], 1);
    __syncthreads();

    // exclusive scan of 64 counts in wave 0 via shfl_up
    if (tid < 64) {
        int v = cnt[tid];
        int incl = v;
#pragma unroll
        for (int d = 1; d < 64; d <<= 1) {
            int u = __shfl_up(incl, d, 64);
            if (tid >= d) incl += u;
        }
        base[tid] = incl - v;
        start[tid] = incl - v;
        if (tid == 63) start[64] = incl;
    }
    __syncthreads();
    if (tid < K_CL) cnt[tid] = base[tid];   // reuse as scatter cursor
    __syncthreads();

    // 8 points per thread via four float4 loads (points 8t..8t+7)
    float4 c0 = reinterpret_cast<const float4*>(coords)[4 * tid + 0];
    float4 c1 = reinterpret_cast<const float4*>(coords)[4 * tid + 1];
    float4 c2 = reinterpret_cast<const float4*>(coords)[4 * tid + 2];
    float4 c3 = reinterpret_cast<const float4*>(coords)[4 * tid + 3];
    float px[8] = {c0.x, c0.z, c1.x, c1.z, c2.x, c2.z, c3.x, c3.z};
    float py[8] = {c0.y, c0.w, c1.y, c1.w, c2.y, c2.w, c3.y, c3.w};
#pragma unroll
    for (int k = 0; k < 8; ++k) {
        int pos = atomicAdd(&cnt[l[k]], 1);
        sx[pos] = px[k];
        sy[pos] = py[k];
    }
}

__global__ void pair_min_kernel(const float* __restrict__ sx,
                                const float* __restrict__ sy,
                                const int* __restrict__ start,
                                float* __restrict__ out) {
    int ci = blockIdx.x, cj = blockIdx.y;
    if (ci >= cj) return;                 // uniform per block
    int iS = start[ci], nI = start[ci + 1] - iS;
    int jS = start[cj], nJ = start[cj + 1] - jS;
    int tid = threadIdx.x;
    __shared__ float jx[256], jy[256];
    float myMin = INF_F;
    for (int i0 = 0; i0 < nI; i0 += 256) {
        bool valid = (i0 + tid) < nI;
        float xi = 0.0f, yi = 0.0f;
        if (valid) { xi = sx[iS + i0 + tid]; yi = sy[iS + i0 + tid]; }
        for (int j0 = 0; j0 < nJ; j0 += 256) {
            __syncthreads();
            if (j0 + tid < nJ) { jx[tid] = sx[jS + j0 + tid]; jy[tid] = sy[jS + j0 + tid]; }
            __syncthreads();
            if (valid) {
                int cnt = min(256, nJ - j0);
                for (int k = 0; k < cnt; ++k) {
                    float dx = xi - jx[k];
                    float dy = yi - jy[k];
                    float d2 = dx * dx + dy * dy;
                    myMin = fminf(myMin, d2);
                }
            }
        }
    }
    // block-reduce min: wave64 shuffle then LDS across 4 waves
    for (int off = 32; off > 0; off >>= 1)
        myMin = fminf(myMin, __shfl_down(myMin, off, 64));
    __shared__ float wmin[4];
    int wave = tid >> 6, lane = tid & 63;
    if (lane == 0) wmin[wave] = myMin;
    __syncthreads();
    if (tid == 0) {
        float m = fminf(fminf(wmin[0], wmin[1]), fminf(wmin[2], wmin[3]));
        float h = 1.0f - sqrtf(m);
        if (h > 0.0f) atomicAdd(out, h * (1.0f / 2016.0f));
    }
}

extern "C" void kernel_launch(void* const* d_in, const int* in_sizes, int n_in,
                              void* d_out, int out_size, void* d_ws, size_t ws_size,
                              hipStream_t stream) {
    const int*   labels = (const int*)d_in[1];     // cluster_labels (int32)
    const float* coords = (const float*)d_in[2];   // manifold_coords [8192,2] f32
    float* out = (float*)d_out;

    float* sx    = (float*)d_ws;
    float* sy    = sx + B_N;
    int*   start = (int*)(sy + B_N);

    hipMemsetAsync(out, 0, sizeof(float) * out_size, stream);
    sort_by_label_kernel<<<1, 1024, 0, stream>>>(labels, coords, sx, sy, start);
    dim3 grid(K_CL, K_CL);
    pair_min_kernel<<<grid, 256, 0, stream>>>(sx, sy, start, out);
}

// Round 3
// 49.027 us; speedup vs baseline: 1.2008x; 1.2008x over previous
//
#include <hip/hip_runtime.h>

#define B_N 8192
#define K_CL 64
#define INF_F 3.0e38f

// ws layout (floats): [0,16384) sorted xy interleaved (float2[8192]) |
// [16384,16449) start offsets (int,65) | [16512,20608) hinges[64*64]

__global__ __launch_bounds__(1024) void sort_by_label_kernel(
    const int* __restrict__ labels, const float* __restrict__ coords,
    float2* __restrict__ sxy, int* __restrict__ start) {
    __shared__ int cnt[K_CL];
    __shared__ int base[K_CL];
    int tid = threadIdx.x;
    if (tid < K_CL) cnt[tid] = 0;
    __syncthreads();

    // 8 labels per thread via two int4 loads (coalesced 16B/lane)
    int4 la = reinterpret_cast<const int4*>(labels)[2 * tid];
    int4 lb = reinterpret_cast<const int4*>(labels)[2 * tid + 1];
    int l[8] = {la.x, la.y, la.z, la.w, lb.x, lb.y, lb.z, lb.w};
#pragma unroll
    for (int k = 0; k < 8; ++k) atomicAdd(&cnt[l[k]], 1);
    __syncthreads();

    // exclusive scan of 64 counts in wave 0 via shfl_up
    if (tid < 64) {
        int v = cnt[tid];
        int incl = v;
#pragma unroll
        for (int d = 1; d < 64; d <<= 1) {
            int u = __shfl_up(incl, d, 64);
            if (tid >= d) incl += u;
        }
        base[tid] = incl - v;
        start[tid] = incl - v;
        if (tid == 63) start[64] = incl;
    }
    __syncthreads();
    if (tid < K_CL) cnt[tid] = base[tid];   // reuse as scatter cursor
    __syncthreads();

    // 8 points per thread via four float4 loads (points 8t..8t+7)
    float4 c0 = reinterpret_cast<const float4*>(coords)[4 * tid + 0];
    float4 c1 = reinterpret_cast<const float4*>(coords)[4 * tid + 1];
    float4 c2 = reinterpret_cast<const float4*>(coords)[4 * tid + 2];
    float4 c3 = reinterpret_cast<const float4*>(coords)[4 * tid + 3];
    float px[8] = {c0.x, c0.z, c1.x, c1.z, c2.x, c2.z, c3.x, c3.z};
    float py[8] = {c0.y, c0.w, c1.y, c1.w, c2.y, c2.w, c3.y, c3.w};
#pragma unroll
    for (int k = 0; k < 8; ++k) {
        int pos = atomicAdd(&cnt[l[k]], 1);
        sxy[pos] = make_float2(px[k], py[k]);
    }
}

__global__ void pair_min_kernel(const float2* __restrict__ sxy,
                                const int* __restrict__ start,
                                float* __restrict__ hinges) {
    int ci = blockIdx.x, cj = blockIdx.y;
    if (ci >= cj) return;                 // uniform per block
    int iS = start[ci], nI = start[ci + 1] - iS;
    int jS = start[cj], nJ = start[cj + 1] - jS;
    int tid = threadIdx.x;
    __shared__ float2 jpt[256];
    float myMin = INF_F;
    for (int i0 = 0; i0 < nI; i0 += 256) {
        bool valid = (i0 + tid) < nI;
        float xi = 0.0f, yi = 0.0f;
        if (valid) { float2 p = sxy[iS + i0 + tid]; xi = p.x; yi = p.y; }
        for (int j0 = 0; j0 < nJ; j0 += 256) {
            __syncthreads();
            if (j0 + tid < nJ) jpt[tid] = sxy[jS + j0 + tid];
            __syncthreads();
            if (valid) {
                int cnt = min(256, nJ - j0);
#pragma unroll 4
                for (int k = 0; k < cnt; ++k) {
                    float2 jp = jpt[k];
                    float dx = xi - jp.x;
                    float dy = yi - jp.y;
                    float d2 = dx * dx + dy * dy;
                    myMin = fminf(myMin, d2);
                }
            }
        }
    }
    // block-reduce min: wave64 shuffle then LDS across 4 waves
    for (int off = 32; off > 0; off >>= 1)
        myMin = fminf(myMin, __shfl_down(myMin, off, 64));
    __shared__ float wmin[4];
    int wave = tid >> 6, lane = tid & 63;
    if (lane == 0) wmin[wave] = myMin;
    __syncthreads();
    if (tid == 0) {
        float m = fminf(fminf(wmin[0], wmin[1]), fminf(wmin[2], wmin[3]));
        float h = 1.0f - sqrtf(m);
        hinges[ci * K_CL + cj] = h > 0.0f ? h : 0.0f;
    }
}

__global__ void reduce_hinge_kernel(const float* __restrict__ hinges,
                                    float* __restrict__ out) {
    int tid = threadIdx.x;
    float s = 0.0f;
    for (int p = tid; p < K_CL * K_CL; p += 256) {
        int ci = p >> 6, cj = p & 63;
        if (ci < cj) s += hinges[p];
    }
    for (int off = 32; off > 0; off >>= 1)
        s += __shfl_down(s, off, 64);
    __shared__ float wsum[4];
    int wave = tid >> 6, lane = tid & 63;
    if (lane == 0) wsum[wave] = s;
    __syncthreads();
    if (tid == 0)
        out[0] = (wsum[0] + wsum[1] + wsum[2] + wsum[3]) / 2016.0f;
}

extern "C" void kernel_launch(void* const* d_in, const int* in_sizes, int n_in,
                              void* d_out, int out_size, void* d_ws, size_t ws_size,
                              hipStream_t stream) {
    const int*   labels = (const int*)d_in[1];     // cluster_labels (int32)
    const float* coords = (const float*)d_in[2];   // manifold_coords [8192,2] f32
    float* out = (float*)d_out;

    float2* sxy   = (float2*)d_ws;
    int*   start  = (int*)((float*)d_ws + 2 * B_N);
    float* hinges = (float*)d_ws + 2 * B_N + 128;

    sort_by_label_kernel<<<1, 1024, 0, stream>>>(labels, coords, sxy, start);
    dim3 grid(K_CL, K_CL);
    pair_min_kernel<<<grid, 256, 0, stream>>>(sxy, start, hinges);
    reduce_hinge_kernel<<<1, 256, 0, stream>>>(hinges, out);
}

// Round 4
// 40.113 us; speedup vs baseline: 1.4677x; 1.2222x over previous
//
#include <hip/hip_runtime.h>

#define B_N 8192
#define K_CL 64
#define INF_F 3.0e38f

// ws layout (floats): [0,8192) sortedX | [8192,16384) sortedY |
// [16384,16449) start offsets (int,65) | [16512,20608) hinges[64*64]

__global__ __launch_bounds__(1024) void sort_by_label_kernel(
    const int* __restrict__ labels, const float* __restrict__ coords,
    float* __restrict__ sx, float* __restrict__ sy, int* __restrict__ start) {
    __shared__ float sxL[B_N];
    __shared__ float syL[B_N];
    __shared__ int hist[K_CL];
    __shared__ int base[K_CL];
    int tid = threadIdx.x;
    if (tid < K_CL) hist[tid] = 0;
    __syncthreads();

    // 8 labels per thread via two int4 loads (coalesced 16B/lane)
    int4 la = reinterpret_cast<const int4*>(labels)[2 * tid];
    int4 lb = reinterpret_cast<const int4*>(labels)[2 * tid + 1];
    int l[8] = {la.x, la.y, la.z, la.w, lb.x, lb.y, lb.z, lb.w};
#pragma unroll
    for (int k = 0; k < 8; ++k) atomicAdd(&hist[l[k]], 1);
    __syncthreads();

    // exclusive scan of 64 counts in wave 0 via shfl_up
    if (tid < 64) {
        int v = hist[tid];
        int incl = v;
#pragma unroll
        for (int d = 1; d < 64; d <<= 1) {
            int u = __shfl_up(incl, d, 64);
            if (tid >= d) incl += u;
        }
        base[tid] = incl - v;
        start[tid] = incl - v;
        if (tid == 63) start[64] = incl;
    }
    __syncthreads();
    if (tid < K_CL) hist[tid] = base[tid];   // reuse as scatter cursor
    __syncthreads();

    // 8 points per thread via four float4 loads (points 8t..8t+7)
    float4 c0 = reinterpret_cast<const float4*>(coords)[4 * tid + 0];
    float4 c1 = reinterpret_cast<const float4*>(coords)[4 * tid + 1];
    float4 c2 = reinterpret_cast<const float4*>(coords)[4 * tid + 2];
    float4 c3 = reinterpret_cast<const float4*>(coords)[4 * tid + 3];
    float px[8] = {c0.x, c0.z, c1.x, c1.z, c2.x, c2.z, c3.x, c3.z};
    float py[8] = {c0.y, c0.w, c1.y, c1.w, c2.y, c2.w, c3.y, c3.w};
    // scatter into LDS (random 4B writes, ~2-way bank alias = free)
#pragma unroll
    for (int k = 0; k < 8; ++k) {
        int pos = atomicAdd(&hist[l[k]], 1);
        sxL[pos] = px[k];
        syL[pos] = py[k];
    }
    __syncthreads();

    // coalesced float4 copy-out of the sorted arrays
    float4* sxg = reinterpret_cast<float4*>(sx);
    float4* syg = reinterpret_cast<float4*>(sy);
    const float4* sxl4 = reinterpret_cast<const float4*>(sxL);
    const float4* syl4 = reinterpret_cast<const float4*>(syL);
    sxg[tid]        = sxl4[tid];
    sxg[tid + 1024] = sxl4[tid + 1024];
    syg[tid]        = syl4[tid];
    syg[tid + 1024] = syl4[tid + 1024];
}

__global__ void pair_min_kernel(const float* __restrict__ sx,
                                const float* __restrict__ sy,
                                const int* __restrict__ start,
                                float* __restrict__ hinges) {
    int ci = blockIdx.x, cj = blockIdx.y;
    if (ci >= cj) return;                 // uniform per block
    int iS = start[ci], nI = start[ci + 1] - iS;
    int jS = start[cj], nJ = start[cj + 1] - jS;
    int tid = threadIdx.x;
    __shared__ float jx[256], jy[256];
    float myMin = INF_F;
    for (int i0 = 0; i0 < nI; i0 += 256) {
        bool valid = (i0 + tid) < nI;
        float xi = 0.0f, yi = 0.0f;
        if (valid) { xi = sx[iS + i0 + tid]; yi = sy[iS + i0 + tid]; }
        for (int j0 = 0; j0 < nJ; j0 += 256) {
            __syncthreads();
            if (j0 + tid < nJ) { jx[tid] = sx[jS + j0 + tid]; jy[tid] = sy[jS + j0 + tid]; }
            __syncthreads();
            if (valid) {
                int cnt = min(256, nJ - j0);
                for (int k = 0; k < cnt; ++k) {
                    float dx = xi - jx[k];
                    float dy = yi - jy[k];
                    float d2 = dx * dx + dy * dy;
                    myMin = fminf(myMin, d2);
                }
            }
        }
    }
    // block-reduce min: wave64 shuffle then LDS across 4 waves
    for (int off = 32; off > 0; off >>= 1)
        myMin = fminf(myMin, __shfl_down(myMin, off, 64));
    __shared__ float wmin[4];
    int wave = tid >> 6, lane = tid & 63;
    if (lane == 0) wmin[wave] = myMin;
    __syncthreads();
    if (tid == 0) {
        float m = fminf(fminf(wmin[0], wmin[1]), fminf(wmin[2], wmin[3]));
        float h = 1.0f - sqrtf(m);
        hinges[ci * K_CL + cj] = h > 0.0f ? h : 0.0f;
    }
}

__global__ void reduce_hinge_kernel(const float* __restrict__ hinges,
                                    float* __restrict__ out) {
    int tid = threadIdx.x;
    float s = 0.0f;
    for (int p = tid; p < K_CL * K_CL; p += 256) {
        int ci = p >> 6, cj = p & 63;
        if (ci < cj) s += hinges[p];
    }
    for (int off = 32; off > 0; off >>= 1)
        s += __shfl_down(s, off, 64);
    __shared__ float wsum[4];
    int wave = tid >> 6, lane = tid & 63;
    if (lane == 0) wsum[wave] = s;
    __syncthreads();
    if (tid == 0)
        out[0] = (wsum[0] + wsum[1] + wsum[2] + wsum[3]) / 2016.0f;
}

extern "C" void kernel_launch(void* const* d_in, const int* in_sizes, int n_in,
                              void* d_out, int out_size, void* d_ws, size_t ws_size,
                              hipStream_t stream) {
    const int*   labels = (const int*)d_in[1];     // cluster_labels (int32)
    const float* coords = (const float*)d_in[2];   // manifold_coords [8192,2] f32
    float* out = (float*)d_out;

    float* sx     = (float*)d_ws;
    float* sy     = sx + B_N;
    int*   start  = (int*)(sy + B_N);
    float* hinges = (float*)d_ws + 2 * B_N + 128;

    sort_by_label_kernel<<<1, 1024, 0, stream>>>(labels, coords, sx, sy, start);
    dim3 grid(K_CL, K_CL);
    pair_min_kernel<<<grid, 256, 0, stream>>>(sx, sy, start, hinges);
    reduce_hinge_kernel<<<1, 256, 0, stream>>>(hinges, out);
}